// Round 5
// baseline (168.514 us; speedup 1.0000x reference)
//
#include <hip/hip_runtime.h>
#include <cstdint>

#define NPOS   32768   // B*H*W
#define KCODE  1024
#define DDIM   256

typedef unsigned long long u64;
typedef unsigned short u16;
typedef __attribute__((ext_vector_type(8))) short short8x;   // 8 bf16 (4 VGPR)
typedef __attribute__((ext_vector_type(4))) float f32x4;     // MFMA acc

__device__ __forceinline__ u16 bf16_rne(float x) {
  unsigned u = __float_as_uint(x);
  return (u16)((u + 0x7fffu + ((u >> 16) & 1u)) >> 16);
}
__device__ __forceinline__ float bf16_tof(u16 h) {
  return __uint_as_float(((unsigned)h) << 16);
}

// ---- kernel 0: pack W into MFMA-fragment-direct layout + wsq ---------------
// Virtual-K: 24 chunks of 32 vd; c 0..7 -> Wh, 8..15 -> Wh (duplicate bytes),
// 16..23 -> Wl.  frag = kh*768 + c*32 + cg*8 + ct; entry frag*64 + lane,
// lane = g*16 + m holds W[code = kh*512+cg*128+ct*16+m][vd = g*8+e], e=0..7.
// The fused kernel reads region 0 once and reuses it for Xh and Xl products.
__global__ void pack_w(const float* __restrict__ w, u16* __restrict__ Wp,
                       float* __restrict__ wsq) {
  const int t = threadIdx.x;              // 256 thr, 8 codes per block
  const int k = blockIdx.x * 8 + (t >> 5);
  const int sub = t & 31;                 // 32 threads per code
  const int g = sub & 3;
  const int dc = sub >> 2;                // d-chunk 0..7
  const int d0 = sub * 8;                 // = dc*32 + g*8
  float x[8];
  *(float4*)(x)     = *(const float4*)(w + (size_t)k * DDIM + d0);
  *(float4*)(x + 4) = *(const float4*)(w + (size_t)k * DDIM + d0 + 4);
  float s = 0.f;
  u16 h[8], lo[8];
  #pragma unroll
  for (int i = 0; i < 8; ++i) {
    s += x[i] * x[i];
    h[i] = bf16_rne(x[i]);
    lo[i] = bf16_rne(x[i] - bf16_tof(h[i]));
  }
  short8x hv, lv;
  #pragma unroll
  for (int i = 0; i < 8; ++i) { hv[i] = (short)h[i]; lv[i] = (short)lo[i]; }
  const int kh = k >> 9, cg = (k >> 7) & 3, ct = (k >> 4) & 7, m = k & 15;
  const int lane = g * 16 + m;
  #pragma unroll
  for (int r = 0; r < 3; ++r) {
    const int c = dc + r * 8;
    const size_t off =
        ((size_t)(kh * 768 + c * 32 + cg * 8 + ct) * 64 + lane) * 8;
    *(short8x*)(Wp + off) = (r < 2) ? hv : lv;
  }
  #pragma unroll
  for (int off = 16; off > 0; off >>= 1) s += __shfl_down(s, off, 32);
  if (sub == 0) wsq[k] = s;
}

// ---- kernel 1 (fused): MFMA dist-GEMM + argmin + gather + out-write --------
// Grid 256 = exactly 1 block/CU (XCD-swizzled), 1024 thr = 16 waves.
// Block: 128 n x all 1024 codes, as TWO 64-n passes sharing ONE prologue:
// all 128 n of z are converted to bf16 hi/lo frags in LDS up front (one
// cold-HBM exposure per CU instead of two). Pass A -> epilogue A (its 32 MB
// of output stores drain under pass B's compute) -> pass B -> epilogue B.
// Hot loop identical to R4's proven 64-arch-VGPR body (4 waves/SIMD).
__global__ __launch_bounds__(1024) void argmin_fused(
    const float* __restrict__ z, const float* __restrict__ w,
    const u16* __restrict__ Wp, const float* __restrict__ wsq,
    float* __restrict__ out) {
  // Xs: 2 halves x {hi,lo} x 8 dc x 4 nt x 64 lane x 8 e u16 = 128 KB.
  // G (gather transpose, 64 KB) aliases half-A (dead when G is live).
  __shared__ __align__(16) char UB[131072];
  __shared__ u64 Red[16][64];                       // 8 KB
  __shared__ int kvs[64];
  u16* Xs = (u16*)UB;
  float* G = (float*)UB;                            // [64][256], col-rotated

  const int tid = threadIdx.x;
  const int l = tid & 63, wv = tid >> 6;
  const int g = l >> 4;

  // XCD swizzle: 256 wgs = 8 XCDs x 32 (bijective)
  const int bid = blockIdx.x;
  const int nb = (bid & 7) * 32 + (bid >> 3);
  const int n0 = nb * 128;
  const int bimg = n0 >> 10, hw0 = n0 & 1023;
  const float* zb = z + (size_t)bimg * (DDIM * 1024) + hw0;

  // ---- prologue: convert z slice (128 n x 256 d) -> bf16 hi/lo frags ----
  // slot (short8x) = h*4096 + hl*2048 + (dc*4 + nt)*64 + gq*16 + mm
  #pragma unroll
  for (int rr = 0; rr < 4; ++rr) {
    const int id = rr * 1024 + tid;
    const int gg = id >> 7;        // d-group 0..31 (8 d each)
    const int nl = id & 127;       // local n (lane-contiguous -> coalesced)
    float x[8];
    #pragma unroll
    for (int e = 0; e < 8; ++e)
      x[e] = zb[(size_t)(gg * 8 + e) * 1024 + nl];
    short8x hv, lv;
    #pragma unroll
    for (int e = 0; e < 8; ++e) {
      u16 hh = bf16_rne(x[e]);
      hv[e] = (short)hh;
      lv[e] = (short)bf16_rne(x[e] - bf16_tof(hh));
    }
    const int h = nl >> 6, n64 = nl & 63;
    const int dc = gg >> 2, gq = gg & 3;
    const int nt = n64 >> 4, mm = n64 & 15;
    const int slot = h * 4096 + (dc * 4 + nt) * 64 + gq * 16 + mm;
    *(short8x*)(&Xs[(size_t)slot * 8]) = hv;
    *(short8x*)(&Xs[(size_t)(slot + 2048) * 8]) = lv;
  }
  __syncthreads();

  // W frag base for wave wv (codes wv*64..+64 as 4 16-code tiles):
  // frag = (kh*24 + c)*32 + cgO*8 + ctO, kh=wv>>3, cgO=(wv>>1)&3, ctO=(wv&1)*4+ct
  const short8x* Wf = (const short8x*)Wp +
      (size_t)((wv >> 3) * 768 + ((wv >> 1) & 3) * 8 + (wv & 1) * 4) * 64 + l;
  const int cbase = wv * 64;
  float4 wq[4];
  #pragma unroll
  for (int ct = 0; ct < 4; ++ct)
    wq[ct] = *(const float4*)(wsq + cbase + ct * 16 + g * 4);

  #pragma unroll 1
  for (int h = 0; h < 2; ++h) {
    const short8x* Xb = (const short8x*)Xs + h * 4096 + l;

    f32x4 acc[4][4];
    #pragma unroll
    for (int ct = 0; ct < 4; ++ct)
      #pragma unroll
      for (int nt = 0; nt < 4; ++nt) acc[ct][nt] = (f32x4){0.f, 0.f, 0.f, 0.f};

    // ---- main loop (R4's proven 64-VGPR body) ----
    #pragma unroll 1
    for (int dc = 0; dc < 8; ++dc) {
      short8x afh[4], afl[4], bfh[4], bfl[4];
      #pragma unroll
      for (int ct = 0; ct < 4; ++ct) afh[ct] = Wf[(dc * 32 + ct) * 64];
      const short8x* Xh = Xb + dc * 256;
      #pragma unroll
      for (int nt = 0; nt < 4; ++nt) bfh[nt] = Xh[nt * 64];
      __builtin_amdgcn_s_setprio(1);
      #pragma unroll
      for (int nt = 0; nt < 4; ++nt)
        #pragma unroll
        for (int ct = 0; ct < 4; ++ct)
          acc[ct][nt] = __builtin_amdgcn_mfma_f32_16x16x32_bf16(
              afh[ct], bfh[nt], acc[ct][nt], 0, 0, 0);
      __builtin_amdgcn_s_setprio(0);
      #pragma unroll
      for (int ct = 0; ct < 4; ++ct) afl[ct] = Wf[((16 + dc) * 32 + ct) * 64];
      __builtin_amdgcn_s_setprio(1);
      #pragma unroll
      for (int nt = 0; nt < 4; ++nt)
        #pragma unroll
        for (int ct = 0; ct < 4; ++ct)
          acc[ct][nt] = __builtin_amdgcn_mfma_f32_16x16x32_bf16(
              afl[ct], bfh[nt], acc[ct][nt], 0, 0, 0);
      __builtin_amdgcn_s_setprio(0);
      const short8x* Xl = Xb + 2048 + dc * 256;
      #pragma unroll
      for (int nt = 0; nt < 4; ++nt) bfl[nt] = Xl[nt * 64];
      __builtin_amdgcn_s_setprio(1);
      #pragma unroll
      for (int nt = 0; nt < 4; ++nt)
        #pragma unroll
        for (int ct = 0; ct < 4; ++ct)
          acc[ct][nt] = __builtin_amdgcn_mfma_f32_16x16x32_bf16(
              afh[ct], bfl[nt], acc[ct][nt], 0, 0, 0);
      __builtin_amdgcn_s_setprio(0);
    }

    // ---- argmin: dist = wsq[k] - 2*dot, packed-key min ----
    #pragma unroll
    for (int nt = 0; nt < 4; ++nt) {
      u64 best = ~0ull;
      #pragma unroll
      for (int ct = 0; ct < 4; ++ct) {
        const float* wqv = (const float*)&wq[ct];
        #pragma unroll
        for (int r = 0; r < 4; ++r) {
          // C/D layout: row(code) = g*4 + r, col(n) = m   [m89-verified]
          float dist = wqv[r] - 2.0f * acc[ct][nt][r];
          unsigned u = __float_as_uint(dist);
          u = (u & 0x80000000u) ? ~u : (u | 0x80000000u);  // monotone order
          u64 key = ((u64)u << 32) | (unsigned)(cbase + ct * 16 + g * 4 + r);
          best = best < key ? best : key;                  // ties -> smallest k
        }
      }
      u64 o = __shfl_xor(best, 16, 64); best = o < best ? o : best;
      o = __shfl_xor(best, 32, 64);     best = o < best ? o : best;
      if (l < 16) Red[wv][nt * 16 + l] = best;   // n64 = nt*16 + m
    }
    __syncthreads();   // Red complete; also: all waves done reading Xs[h]

    if (tid < 64) {
      u64 best = Red[0][tid];
      #pragma unroll
      for (int ww = 1; ww < 16; ++ww) {
        u64 o = Red[ww][tid];
        best = o < best ? o : best;
      }
      kvs[tid] = (int)(best & 0xffffffffull);
    }
    __syncthreads();   // kvs ready; epilogue-A G-reads (prev h) long done

    // ---- gather winning w rows into G[n][(c+n)&255] (col-rotated) ----
    // G aliases Xs half-A, which is dead (h=0: just consumed; h=1: stale).
    #pragma unroll
    for (int i = 0; i < 4; ++i) {
      const int n = wv * 4 + i;
      const int k = kvs[n];
      const float* wr = w + (size_t)k * DDIM;
      #pragma unroll
      for (int j = 0; j < 4; ++j) {
        const int c = l + 64 * j;                 // coalesced 256B reads
        G[n * 256 + ((c + n) & 255)] = wr[c];     // bank (c+n)&31: 2-way max
      }
    }
    __syncthreads();

    // ---- out-write: row n = l, coalesced 256B per instr ----
    float* oc = out + (size_t)bimg * (DDIM * 1024) + hw0 + h * 64;
    #pragma unroll
    for (int cc = 0; cc < 16; ++cc) {
      const int c = cc * 16 + wv;
      float v = G[l * 256 + ((c + l) & 255)];     // bank (c+l)&31: 2-way max
      oc[(size_t)c * 1024 + l] = v;               // codes
      oc[(size_t)c * 1024 + l + 8388608] = v;     // codes_bar
    }
    // no trailing barrier needed: pass B touches only Xs half-B and Red
    // (Red reuse is fenced by the post-Red __syncthreads above).
  }
}

// ======================= fallback path (small workspace) ====================

__global__ void wt_kernel(const float* __restrict__ w, float* __restrict__ wt) {
  __shared__ float T[64][65];
  const int k0 = blockIdx.x * 64;
  const int d0 = blockIdx.y * 64;
  const int c = threadIdx.x & 63;
  const int r = threadIdx.x >> 6;
  #pragma unroll
  for (int p = 0; p < 16; ++p)
    T[p * 4 + r][c] = w[(size_t)(k0 + p * 4 + r) * DDIM + d0 + c];
  __syncthreads();
  #pragma unroll
  for (int p = 0; p < 16; ++p)
    wt[(size_t)(d0 + p * 4 + r) * KCODE + k0 + c] = T[c][p * 4 + r];
}

__global__ __launch_bounds__(512, 2) void argmin_mfma_v2(
    const float* __restrict__ z, const u16* __restrict__ Wp,
    const float* __restrict__ wsq, int* __restrict__ idx) {
  __shared__ __align__(16) u16 Xs[2 * 8 * 8 * 64 * 8];   // 128 KB
  __shared__ u64 Red[8][128];

  const int tid = threadIdx.x;
  const int l = tid & 63, wv = tid >> 6;
  const int g = l >> 4;

  const int bid = blockIdx.x;
  const int nb = (bid & 7) * 32 + (bid >> 3);
  const int n0 = nb * 128;
  const int bimg = n0 >> 10, hw0 = n0 & 1023;
  const float* zb = z + (size_t)bimg * (DDIM * 1024) + hw0;

  #pragma unroll
  for (int rr = 0; rr < 8; ++rr) {
    const int id = rr * 512 + tid;
    const int gg = id >> 7;
    const int nl = id & 127;
    float x[8];
    #pragma unroll
    for (int e = 0; e < 8; ++e)
      x[e] = zb[(size_t)(gg * 8 + e) * 1024 + nl];
    short8x hv, lv;
    #pragma unroll
    for (int e = 0; e < 8; ++e) {
      u16 hh = bf16_rne(x[e]);
      hv[e] = (short)hh;
      lv[e] = (short)bf16_rne(x[e] - bf16_tof(hh));
    }
    const int dc = gg >> 2, gq = gg & 3;
    const int nt = nl >> 4, mm = nl & 15;
    const int slot = (dc * 8 + nt) * 64 + gq * 16 + mm;
    *(short8x*)(&Xs[(size_t)slot * 8]) = hv;
    *(short8x*)(&Xs[(size_t)(slot + 4096) * 8]) = lv;
  }
  __syncthreads();

  // fallback uses the SAME Wp layout as pack_w above (kh*768 + c*32 + cg*8 + ct)
  const short8x* WfBase =
      (const short8x*)Wp + (size_t)(((wv >> 1) & 3) * 8 + (wv & 1) * 4) * 64 + l;

  #pragma unroll 1
  for (int khp = 0; khp < 2; ++khp) {
    const short8x* Wf = WfBase + (size_t)khp * 49152;

    f32x4 acc[4][8];
    #pragma unroll
    for (int ct = 0; ct < 4; ++ct)
      #pragma unroll
      for (int nt = 0; nt < 8; ++nt) acc[ct][nt] = (f32x4){0.f, 0.f, 0.f, 0.f};

    #pragma unroll 1
    for (int dc = 0; dc < 8; ++dc) {
      short8x afh[4], afl[4];
      #pragma unroll
      for (int ct = 0; ct < 4; ++ct) afh[ct] = Wf[(dc * 32 + ct) * 64];
      const short8x* Xh = (const short8x*)Xs + dc * 512 + l;
      short8x bfh[8], bfl[8];
      #pragma unroll
      for (int nt = 0; nt < 8; ++nt) bfh[nt] = Xh[nt * 64];
      #pragma unroll
      for (int nt = 0; nt < 8; ++nt)
        #pragma unroll
        for (int ct = 0; ct < 4; ++ct)
          acc[ct][nt] = __builtin_amdgcn_mfma_f32_16x16x32_bf16(
              afh[ct], bfh[nt], acc[ct][nt], 0, 0, 0);
      #pragma unroll
      for (int ct = 0; ct < 4; ++ct) afl[ct] = Wf[((16 + dc) * 32 + ct) * 64];
      #pragma unroll
      for (int nt = 0; nt < 8; ++nt)
        #pragma unroll
        for (int ct = 0; ct < 4; ++ct)
          acc[ct][nt] = __builtin_amdgcn_mfma_f32_16x16x32_bf16(
              afl[ct], bfh[nt], acc[ct][nt], 0, 0, 0);
      const short8x* Xl = (const short8x*)Xs + 4096 + dc * 512 + l;
      #pragma unroll
      for (int nt = 0; nt < 8; ++nt) bfl[nt] = Xl[nt * 64];
      #pragma unroll
      for (int nt = 0; nt < 8; ++nt)
        #pragma unroll
        for (int ct = 0; ct < 4; ++ct)
          acc[ct][nt] = __builtin_amdgcn_mfma_f32_16x16x32_bf16(
              afh[ct], bfl[nt], acc[ct][nt], 0, 0, 0);
    }

    const int cbase = khp * 512 + wv * 64;
    float4 wq[4];
    #pragma unroll
    for (int ct = 0; ct < 4; ++ct)
      wq[ct] = *(const float4*)(wsq + cbase + ct * 16 + g * 4);

    #pragma unroll
    for (int nt = 0; nt < 8; ++nt) {
      u64 best = ~0ull;
      #pragma unroll
      for (int ct = 0; ct < 4; ++ct) {
        const float* wqv = (const float*)&wq[ct];
        #pragma unroll
        for (int r = 0; r < 4; ++r) {
          float dist = wqv[r] - 2.0f * acc[ct][nt][r];
          unsigned u = __float_as_uint(dist);
          u = (u & 0x80000000u) ? ~u : (u | 0x80000000u);
          u64 key = ((u64)u << 32) | (unsigned)(cbase + ct * 16 + g * 4 + r);
          best = best < key ? best : key;
        }
      }
      u64 o = __shfl_xor(best, 16, 64); best = o < best ? o : best;
      o = __shfl_xor(best, 32, 64);     best = o < best ? o : best;
      if (l < 16) {
        const int j = nt * 16 + l;
        if (khp == 0) Red[wv][j] = best;
        else { u64 p = Red[wv][j]; Red[wv][j] = best < p ? best : p; }
      }
    }
  }

  __syncthreads();
  if (tid < 128) {
    u64 best = Red[0][tid];
    #pragma unroll
    for (int ww = 1; ww < 8; ++ww) {
      u64 o = Red[ww][tid];
      best = o < best ? o : best;
    }
    idx[n0 + tid] = (int)(best & 0xffffffffull);
  }
}

#define WPITCH 1028
__global__ __launch_bounds__(256) void gather2_kernel(
    const float* __restrict__ wt, const int* __restrict__ idx,
    float* __restrict__ out) {
  __shared__ __align__(16) float Ws[16 * WPITCH];
  const int tid = threadIdx.x;
  const int bimg = blockIdx.x >> 4;
  const int c0 = (blockIdx.x & 15) * 16;
  int4 kv = *(const int4*)(idx + bimg * 1024 + tid * 4);
  #pragma unroll
  for (int cc = 0; cc < 16; ++cc) {
    float4 v = *(const float4*)(wt + (size_t)(c0 + cc) * KCODE + tid * 4);
    *(float4*)(Ws + cc * WPITCH + tid * 4) = v;
  }
  __syncthreads();
  float* ob = out + (size_t)bimg * DDIM * 1024 + (size_t)c0 * 1024 + tid * 4;
  #pragma unroll
  for (int cc = 0; cc < 16; ++cc) {
    const float* wr = Ws + cc * WPITCH;
    float4 v;
    v.x = wr[kv.x]; v.y = wr[kv.y]; v.z = wr[kv.z]; v.w = wr[kv.w];
    *(float4*)(ob + (size_t)cc * 1024) = v;               // codes
    *(float4*)(ob + (size_t)cc * 1024 + 8388608) = v;     // codes_bar
  }
}

__global__ void gather_kernel(const float* __restrict__ w, const int* __restrict__ idx,
                              float* __restrict__ out) {
  const int gi = blockIdx.x * 256 + threadIdx.x;
  const int hw4 = gi & 255;
  const int c = (gi >> 8) & 255;
  const int b = gi >> 16;
  int4 kv = *(const int4*)(idx + b * 1024 + hw4 * 4);
  float4 v;
  v.x = w[(size_t)kv.x * 256 + c];
  v.y = w[(size_t)kv.y * 256 + c];
  v.z = w[(size_t)kv.z * 256 + c];
  v.w = w[(size_t)kv.w * 256 + c];
  float4* o = (float4*)out;
  o[gi] = v;
  o[gi + 2097152] = v;
}

extern "C" void kernel_launch(void* const* d_in, const int* in_sizes, int n_in,
                              void* d_out, int out_size, void* d_ws, size_t ws_size,
                              hipStream_t stream) {
  const float* z = (const float*)d_in[0];   // [32,256,32,32] fp32
  const float* w = (const float*)d_in[1];   // [1024,256] fp32
  float* out = (float*)d_out;

  float* wsq = (float*)d_ws;                 // 4 KB @ 0
  const size_t need_fused = 4096 + 1572864;  // wsq + Wp (1.5 MB)

  if (ws_size >= need_fused) {
    u16* Wp = (u16*)((char*)d_ws + 4096);
    pack_w<<<128, 256, 0, stream>>>(w, Wp, wsq);
    argmin_fused<<<256, 1024, 0, stream>>>(z, w, Wp, wsq, out);
    return;
  }

  // -------- fallback: R2-style pipeline (Wp scratch inside codes_bar) -------
  int* idx = (int*)((char*)d_ws + 4096);     // 128 KB @ 4 KB
  const size_t need = 4096 + 131072 + 1048576;
  const bool ws_ok = ws_size >= need;
  float* wt = ws_ok ? (float*)((char*)d_ws + 4096 + 131072)
                    : out + (size_t)out_size - 262144;
  u16* Wp = (u16*)(out + 8388608);           // codes_bar scratch (consumed pre-gather)

  pack_w<<<128, 256, 0, stream>>>(w, Wp, wsq);
  wt_kernel<<<dim3(16, 4), 256, 0, stream>>>(w, wt);
  argmin_mfma_v2<<<256, 512, 0, stream>>>(z, Wp, wsq, idx);
  if (ws_ok)
    gather2_kernel<<<512, 256, 0, stream>>>(wt, idx, out);
  else
    gather_kernel<<<2097152 / 256, 256, 0, stream>>>(w, idx, out);
}

// Round 6
// 137.102 us; speedup vs baseline: 1.2291x; 1.2291x over previous
//
#include <hip/hip_runtime.h>
#include <cstdint>

#define NPOS   32768   // B*H*W
#define KCODE  1024
#define DDIM   256

typedef unsigned long long u64;
typedef unsigned short u16;
typedef __attribute__((ext_vector_type(8))) short short8x;   // 8 bf16 (4 VGPR)
typedef __attribute__((ext_vector_type(4))) float f32x4;     // MFMA acc

__device__ __forceinline__ u16 bf16_rne(float x) {
  unsigned u = __float_as_uint(x);
  return (u16)((u + 0x7fffu + ((u >> 16) & 1u)) >> 16);
}
__device__ __forceinline__ float bf16_tof(u16 h) {
  return __uint_as_float(((unsigned)h) << 16);
}

// ---- kernel 0: pack W into MFMA-fragment-direct layout + wsq ---------------
// Virtual-K: 24 chunks of 32 vd; c 0..7 -> Wh, 8..15 -> Wh (duplicate bytes),
// 16..23 -> Wl.  frag = kh*768 + c*32 + cg*8 + ct; entry frag*64 + lane,
// lane = g*16 + m holds W[code = kh*512+cg*128+ct*16+m][vd = g*8+e], e=0..7.
// The fused kernel reads region 0 once and reuses it for Xh and Xl products.
__global__ void pack_w(const float* __restrict__ w, u16* __restrict__ Wp,
                       float* __restrict__ wsq) {
  const int t = threadIdx.x;              // 256 thr, 8 codes per block
  const int k = blockIdx.x * 8 + (t >> 5);
  const int sub = t & 31;                 // 32 threads per code
  const int g = sub & 3;
  const int dc = sub >> 2;                // d-chunk 0..7
  const int d0 = sub * 8;                 // = dc*32 + g*8
  float x[8];
  *(float4*)(x)     = *(const float4*)(w + (size_t)k * DDIM + d0);
  *(float4*)(x + 4) = *(const float4*)(w + (size_t)k * DDIM + d0 + 4);
  float s = 0.f;
  u16 h[8], lo[8];
  #pragma unroll
  for (int i = 0; i < 8; ++i) {
    s += x[i] * x[i];
    h[i] = bf16_rne(x[i]);
    lo[i] = bf16_rne(x[i] - bf16_tof(h[i]));
  }
  short8x hv, lv;
  #pragma unroll
  for (int i = 0; i < 8; ++i) { hv[i] = (short)h[i]; lv[i] = (short)lo[i]; }
  const int kh = k >> 9, cg = (k >> 7) & 3, ct = (k >> 4) & 7, m = k & 15;
  const int lane = g * 16 + m;
  #pragma unroll
  for (int r = 0; r < 3; ++r) {
    const int c = dc + r * 8;
    const size_t off =
        ((size_t)(kh * 768 + c * 32 + cg * 8 + ct) * 64 + lane) * 8;
    *(short8x*)(Wp + off) = (r < 2) ? hv : lv;
  }
  #pragma unroll
  for (int off = 16; off > 0; off >>= 1) s += __shfl_down(s, off, 32);
  if (sub == 0) wsq[k] = s;
}

// ---- kernel 1 (fused): MFMA dist-GEMM + argmin + gather + out-write --------
// R4 structure (proven cleanest HBM traffic: 96 MB total): grid 512, 1024 thr
// = 16 waves, block = 1024 codes x 64 n, wave = 64 codes x 64 n, acc[4][4].
// Unified regs/wave = 64 arch + 64 acc = 128 -> 4 waves/SIMD, 1 block/CU
// resident at a time.
// R6 edits (anti-convoy scheduling; zero layout/traffic change):
//  - wave-staggered dc start: SIMD-mates (wv, wv+4, wv+8, wv+12) begin at 4
//    different loop phases, so one wave's L2/L3 wait overlaps mates' MFMA.
//  - per dc: issue afh+afl+bfh up front; region order hh -> hl -> lh gives
//    afl ~32 MFMA of latency cover (was 0).
//  - setprio removed (null-to-negative on homogeneous lockstep loops, m190).
__global__ __launch_bounds__(1024) void argmin_fused(
    const float* __restrict__ z, const float* __restrict__ w,
    const u16* __restrict__ Wp, const float* __restrict__ wsq,
    float* __restrict__ out) {
  // union: X frags (64 KB) then padded gather buffer G[64][257] (65792 B)
  __shared__ __align__(16) char UB[64 * 257 * 4];
  __shared__ u64 Red[16][64];                       // 8 KB
  __shared__ int kvs[64];
  u16* Xs = (u16*)UB;
  float* G = (float*)UB;

  const int tid = threadIdx.x;
  const int l = tid & 63, wv = tid >> 6;
  const int g = l >> 4;

  // XCD swizzle: 512 wgs = 8 XCDs x 64 (bijective)
  const int bid = blockIdx.x;
  const int nb = (bid & 7) * 64 + (bid >> 3);
  const int n0 = nb * 64;
  const int bimg = n0 >> 10, hw0 = n0 & 1023;
  const float* zb = z + (size_t)bimg * (DDIM * 1024) + hw0;

  // ---- prologue: convert z slice (64 n x 256 d) -> bf16 hi/lo frags ----
  // slot (short8x) = hl*2048 + (dc*4 + nt)*64 + gq*16 + mm
  #pragma unroll
  for (int rr = 0; rr < 2; ++rr) {
    const int id = rr * 1024 + tid;
    const int gg = id >> 6;        // d-group 0..31 (8 d each)
    const int nl = id & 63;        // local n (lane-contiguous -> coalesced)
    float x[8];
    #pragma unroll
    for (int e = 0; e < 8; ++e)
      x[e] = zb[(size_t)(gg * 8 + e) * 1024 + nl];
    short8x hv, lv;
    #pragma unroll
    for (int e = 0; e < 8; ++e) {
      u16 hh = bf16_rne(x[e]);
      hv[e] = (short)hh;
      lv[e] = (short)bf16_rne(x[e] - bf16_tof(hh));
    }
    const int dc = gg >> 2, gq = gg & 3;
    const int nt = nl >> 4, mm = nl & 15;
    const int slot = (dc * 4 + nt) * 64 + gq * 16 + mm;   // short8x units
    *(short8x*)(&Xs[(size_t)slot * 8]) = hv;
    *(short8x*)(&Xs[(size_t)(slot + 2048) * 8]) = lv;
  }
  __syncthreads();   // Xs read-only from here until after the argmin barrier

  // W frag base for wave wv (codes wv*64..+64 as 4 16-code tiles):
  // frag = (kh*24 + c)*32 + cgO*8 + ctO, kh=wv>>3, cgO=(wv>>1)&3, ctO=(wv&1)*4+ct
  const short8x* Wf = (const short8x*)Wp +
      (size_t)((wv >> 3) * 768 + ((wv >> 1) & 3) * 8 + (wv & 1) * 4) * 64 + l;

  f32x4 acc[4][4];
  #pragma unroll
  for (int ct = 0; ct < 4; ++ct)
    #pragma unroll
    for (int nt = 0; nt < 4; ++nt) acc[ct][nt] = (f32x4){0.f, 0.f, 0.f, 0.f};

  // anti-convoy stagger: SIMD-mates {wv, wv+4, wv+8, wv+12} -> 4 phases
  const int ph = (wv >> 2) * 2;

  #pragma unroll 1
  for (int it = 0; it < 8; ++it) {
    const int dc = (it + ph) & 7;
    short8x afh[4], afl[4], bfh[4], bfl[4];
    // issue both W streams up front: afl gets ~32 MFMA of cover before lh
    #pragma unroll
    for (int ct = 0; ct < 4; ++ct) afh[ct] = Wf[(dc * 32 + ct) * 64];
    #pragma unroll
    for (int ct = 0; ct < 4; ++ct) afl[ct] = Wf[((16 + dc) * 32 + ct) * 64];
    const short8x* Xh = (const short8x*)Xs + dc * 256 + l;
    #pragma unroll
    for (int nt = 0; nt < 4; ++nt) bfh[nt] = Xh[nt * 64];
    // region hh: Wh x Xh
    #pragma unroll
    for (int nt = 0; nt < 4; ++nt)
      #pragma unroll
      for (int ct = 0; ct < 4; ++ct)
        acc[ct][nt] = __builtin_amdgcn_mfma_f32_16x16x32_bf16(
            afh[ct], bfh[nt], acc[ct][nt], 0, 0, 0);
    const short8x* Xl = (const short8x*)Xs + 2048 + dc * 256 + l;
    #pragma unroll
    for (int nt = 0; nt < 4; ++nt) bfl[nt] = Xl[nt * 64];
    // region hl: Wh x Xl
    #pragma unroll
    for (int nt = 0; nt < 4; ++nt)
      #pragma unroll
      for (int ct = 0; ct < 4; ++ct)
        acc[ct][nt] = __builtin_amdgcn_mfma_f32_16x16x32_bf16(
            afh[ct], bfl[nt], acc[ct][nt], 0, 0, 0);
    // region lh: Wl x Xh (afl long since landed)
    #pragma unroll
    for (int nt = 0; nt < 4; ++nt)
      #pragma unroll
      for (int ct = 0; ct < 4; ++ct)
        acc[ct][nt] = __builtin_amdgcn_mfma_f32_16x16x32_bf16(
            afl[ct], bfh[nt], acc[ct][nt], 0, 0, 0);
  }

  // ---- epilogue: dist = wsq[k] - 2*dot, packed-key argmin ----
  const int cbase = wv * 64;
  float4 wq[4];
  #pragma unroll
  for (int ct = 0; ct < 4; ++ct)
    wq[ct] = *(const float4*)(wsq + cbase + ct * 16 + g * 4);

  #pragma unroll
  for (int nt = 0; nt < 4; ++nt) {
    u64 best = ~0ull;
    #pragma unroll
    for (int ct = 0; ct < 4; ++ct) {
      const float* wqv = (const float*)&wq[ct];
      #pragma unroll
      for (int r = 0; r < 4; ++r) {
        // C/D layout: row(code) = g*4 + r, col(n) = m   [m89-verified]
        float dist = wqv[r] - 2.0f * acc[ct][nt][r];
        unsigned u = __float_as_uint(dist);
        u = (u & 0x80000000u) ? ~u : (u | 0x80000000u);  // monotone order
        u64 key = ((u64)u << 32) | (unsigned)(cbase + ct * 16 + g * 4 + r);
        best = best < key ? best : key;                  // ties -> smallest k
      }
    }
    u64 o = __shfl_xor(best, 16, 64); best = o < best ? o : best;
    o = __shfl_xor(best, 32, 64);     best = o < best ? o : best;
    if (l < 16) Red[wv][nt * 16 + l] = best;   // j = nt*16 + m
  }
  __syncthreads();   // all waves done with Xs + Red complete

  if (tid < 64) {
    u64 best = Red[0][tid];
    #pragma unroll
    for (int ww = 1; ww < 16; ++ww) {
      u64 o = Red[ww][tid];
      best = o < best ? o : best;
    }
    kvs[tid] = (int)(best & 0xffffffffull);
  }
  __syncthreads();

  // ---- gather: stage winning w rows into G[n][c] (pitch 257, fp32) ----
  #pragma unroll
  for (int i = 0; i < 4; ++i) {
    const int n = wv * 4 + i;
    const int k = kvs[n];
    float4 vv = *(const float4*)(w + (size_t)k * DDIM + l * 4);
    *(float4*)(&G[n * 257 + l * 4]) = vv;   // lane l -> c = l*4..l*4+3
  }
  __syncthreads();

  // ---- write out: coalesced per-c rows; bank-rotated column reads ----
  float* oc = out + (size_t)bimg * (DDIM * 1024) + hw0;
  #pragma unroll
  for (int cc = 0; cc < 16; ++cc) {
    const int c = cc * 16 + wv;
    float v = G[l * 257 + c];               // bank = (l + c) & 31: conflict-free
    oc[(size_t)c * 1024 + l] = v;           // codes
    oc[(size_t)c * 1024 + l + 8388608] = v; // codes_bar
  }
}

// ======================= fallback path (small workspace) ====================

__global__ void wt_kernel(const float* __restrict__ w, float* __restrict__ wt) {
  __shared__ float T[64][65];
  const int k0 = blockIdx.x * 64;
  const int d0 = blockIdx.y * 64;
  const int c = threadIdx.x & 63;
  const int r = threadIdx.x >> 6;
  #pragma unroll
  for (int p = 0; p < 16; ++p)
    T[p * 4 + r][c] = w[(size_t)(k0 + p * 4 + r) * DDIM + d0 + c];
  __syncthreads();
  #pragma unroll
  for (int p = 0; p < 16; ++p)
    wt[(size_t)(d0 + p * 4 + r) * KCODE + k0 + c] = T[c][p * 4 + r];
}

__global__ __launch_bounds__(512, 2) void argmin_mfma_v2(
    const float* __restrict__ z, const u16* __restrict__ Wp,
    const float* __restrict__ wsq, int* __restrict__ idx) {
  __shared__ __align__(16) u16 Xs[2 * 8 * 8 * 64 * 8];   // 128 KB
  __shared__ u64 Red[8][128];

  const int tid = threadIdx.x;
  const int l = tid & 63, wv = tid >> 6;
  const int g = l >> 4;

  const int bid = blockIdx.x;
  const int nb = (bid & 7) * 32 + (bid >> 3);
  const int n0 = nb * 128;
  const int bimg = n0 >> 10, hw0 = n0 & 1023;
  const float* zb = z + (size_t)bimg * (DDIM * 1024) + hw0;

  #pragma unroll
  for (int rr = 0; rr < 8; ++rr) {
    const int id = rr * 512 + tid;
    const int gg = id >> 7;
    const int nl = id & 127;
    float x[8];
    #pragma unroll
    for (int e = 0; e < 8; ++e)
      x[e] = zb[(size_t)(gg * 8 + e) * 1024 + nl];
    short8x hv, lv;
    #pragma unroll
    for (int e = 0; e < 8; ++e) {
      u16 hh = bf16_rne(x[e]);
      hv[e] = (short)hh;
      lv[e] = (short)bf16_rne(x[e] - bf16_tof(hh));
    }
    const int dc = gg >> 2, gq = gg & 3;
    const int nt = nl >> 4, mm = nl & 15;
    const int slot = (dc * 8 + nt) * 64 + gq * 16 + mm;
    *(short8x*)(&Xs[(size_t)slot * 8]) = hv;
    *(short8x*)(&Xs[(size_t)(slot + 4096) * 8]) = lv;
  }
  __syncthreads();

  const short8x* WfBase =
      (const short8x*)Wp + (size_t)(((wv >> 1) & 3) * 8 + (wv & 1) * 4) * 64 + l;

  #pragma unroll 1
  for (int khp = 0; khp < 2; ++khp) {
    const short8x* Wf = WfBase + (size_t)khp * 49152;

    f32x4 acc[4][8];
    #pragma unroll
    for (int ct = 0; ct < 4; ++ct)
      #pragma unroll
      for (int nt = 0; nt < 8; ++nt) acc[ct][nt] = (f32x4){0.f, 0.f, 0.f, 0.f};

    #pragma unroll 1
    for (int dc = 0; dc < 8; ++dc) {
      short8x afh[4], afl[4];
      #pragma unroll
      for (int ct = 0; ct < 4; ++ct) afh[ct] = Wf[(dc * 32 + ct) * 64];
      const short8x* Xh = (const short8x*)Xs + dc * 512 + l;
      short8x bfh[8], bfl[8];
      #pragma unroll
      for (int nt = 0; nt < 8; ++nt) bfh[nt] = Xh[nt * 64];
      #pragma unroll
      for (int nt = 0; nt < 8; ++nt)
        #pragma unroll
        for (int ct = 0; ct < 4; ++ct)
          acc[ct][nt] = __builtin_amdgcn_mfma_f32_16x16x32_bf16(
              afh[ct], bfh[nt], acc[ct][nt], 0, 0, 0);
      #pragma unroll
      for (int ct = 0; ct < 4; ++ct) afl[ct] = Wf[((16 + dc) * 32 + ct) * 64];
      #pragma unroll
      for (int nt = 0; nt < 8; ++nt)
        #pragma unroll
        for (int ct = 0; ct < 4; ++ct)
          acc[ct][nt] = __builtin_amdgcn_mfma_f32_16x16x32_bf16(
              afl[ct], bfh[nt], acc[ct][nt], 0, 0, 0);
      const short8x* Xl = (const short8x*)Xs + 4096 + dc * 512 + l;
      #pragma unroll
      for (int nt = 0; nt < 8; ++nt) bfl[nt] = Xl[nt * 64];
      #pragma unroll
      for (int nt = 0; nt < 8; ++nt)
        #pragma unroll
        for (int ct = 0; ct < 4; ++ct)
          acc[ct][nt] = __builtin_amdgcn_mfma_f32_16x16x32_bf16(
              afh[ct], bfl[nt], acc[ct][nt], 0, 0, 0);
    }

    const int cbase = khp * 512 + wv * 64;
    float4 wq[4];
    #pragma unroll
    for (int ct = 0; ct < 4; ++ct)
      wq[ct] = *(const float4*)(wsq + cbase + ct * 16 + g * 4);

    #pragma unroll
    for (int nt = 0; nt < 8; ++nt) {
      u64 best = ~0ull;
      #pragma unroll
      for (int ct = 0; ct < 4; ++ct) {
        const float* wqv = (const float*)&wq[ct];
        #pragma unroll
        for (int r = 0; r < 4; ++r) {
          float dist = wqv[r] - 2.0f * acc[ct][nt][r];
          unsigned u = __float_as_uint(dist);
          u = (u & 0x80000000u) ? ~u : (u | 0x80000000u);
          u64 key = ((u64)u << 32) | (unsigned)(cbase + ct * 16 + g * 4 + r);
          best = best < key ? best : key;
        }
      }
      u64 o = __shfl_xor(best, 16, 64); best = o < best ? o : best;
      o = __shfl_xor(best, 32, 64);     best = o < best ? o : best;
      if (l < 16) {
        const int j = nt * 16 + l;
        if (khp == 0) Red[wv][j] = best;
        else { u64 p = Red[wv][j]; Red[wv][j] = best < p ? best : p; }
      }
    }
  }

  __syncthreads();
  if (tid < 128) {
    u64 best = Red[0][tid];
    #pragma unroll
    for (int ww = 1; ww < 8; ++ww) {
      u64 o = Red[ww][tid];
      best = o < best ? o : best;
    }
    idx[n0 + tid] = (int)(best & 0xffffffffull);
  }
}

#define WPITCH 1028
__global__ __launch_bounds__(256) void gather2_kernel(
    const float* __restrict__ wt, const int* __restrict__ idx,
    float* __restrict__ out) {
  __shared__ __align__(16) float Ws[16 * WPITCH];
  const int tid = threadIdx.x;
  const int bimg = blockIdx.x >> 4;
  const int c0 = (blockIdx.x & 15) * 16;
  int4 kv = *(const int4*)(idx + bimg * 1024 + tid * 4);
  #pragma unroll
  for (int cc = 0; cc < 16; ++cc) {
    float4 v = *(const float4*)(wt + (size_t)(c0 + cc) * KCODE + tid * 4);
    *(float4*)(Ws + cc * WPITCH + tid * 4) = v;
  }
  __syncthreads();
  float* ob = out + (size_t)bimg * DDIM * 1024 + (size_t)c0 * 1024 + tid * 4;
  #pragma unroll
  for (int cc = 0; cc < 16; ++cc) {
    const float* wr = Ws + cc * WPITCH;
    float4 v;
    v.x = wr[kv.x]; v.y = wr[kv.y]; v.z = wr[kv.z]; v.w = wr[kv.w];
    *(float4*)(ob + (size_t)cc * 1024) = v;               // codes
    *(float4*)(ob + (size_t)cc * 1024 + 8388608) = v;     // codes_bar
  }
}

__global__ void gather_kernel(const float* __restrict__ w, const int* __restrict__ idx,
                              float* __restrict__ out) {
  const int gi = blockIdx.x * 256 + threadIdx.x;
  const int hw4 = gi & 255;
  const int c = (gi >> 8) & 255;
  const int b = gi >> 16;
  int4 kv = *(const int4*)(idx + b * 1024 + hw4 * 4);
  float4 v;
  v.x = w[(size_t)kv.x * 256 + c];
  v.y = w[(size_t)kv.y * 256 + c];
  v.z = w[(size_t)kv.z * 256 + c];
  v.w = w[(size_t)kv.w * 256 + c];
  float4* o = (float4*)out;
  o[gi] = v;
  o[gi + 2097152] = v;
}

extern "C" void kernel_launch(void* const* d_in, const int* in_sizes, int n_in,
                              void* d_out, int out_size, void* d_ws, size_t ws_size,
                              hipStream_t stream) {
  const float* z = (const float*)d_in[0];   // [32,256,32,32] fp32
  const float* w = (const float*)d_in[1];   // [1024,256] fp32
  float* out = (float*)d_out;

  float* wsq = (float*)d_ws;                 // 4 KB @ 0
  const size_t need_fused = 4096 + 1572864;  // wsq + Wp (1.5 MB)

  if (ws_size >= need_fused) {
    u16* Wp = (u16*)((char*)d_ws + 4096);
    pack_w<<<128, 256, 0, stream>>>(w, Wp, wsq);
    argmin_fused<<<512, 1024, 0, stream>>>(z, w, Wp, wsq, out);
    return;
  }

  // -------- fallback: R2-style pipeline (Wp scratch inside codes_bar) -------
  int* idx = (int*)((char*)d_ws + 4096);     // 128 KB @ 4 KB
  const size_t need = 4096 + 131072 + 1048576;
  const bool ws_ok = ws_size >= need;
  float* wt = ws_ok ? (float*)((char*)d_ws + 4096 + 131072)
                    : out + (size_t)out_size - 262144;
  u16* Wp = (u16*)(out + 8388608);           // codes_bar scratch (consumed pre-gather)

  pack_w<<<128, 256, 0, stream>>>(w, Wp, wsq);
  wt_kernel<<<dim3(16, 4), 256, 0, stream>>>(w, wt);
  argmin_mfma_v2<<<256, 512, 0, stream>>>(z, Wp, wsq, idx);
  if (ws_ok)
    gather2_kernel<<<512, 256, 0, stream>>>(wt, idx, out);
  else
    gather_kernel<<<2097152 / 256, 256, 0, stream>>>(w, idx, out);
}